// Round 8
// baseline (1126.281 us; speedup 1.0000x reference)
//
#include <hip/hip_runtime.h>
#include <hip/hip_bf16.h>

#define NT 8192      // tokens
#define DM 1024      // d_model
#define NE 8         // experts
#define DH 4096      // d_hidden
#define NP (NT * 2)  // token-expert pairs (TOP_K = 2)

typedef __attribute__((ext_vector_type(8))) __bf16 bf16x8;
typedef __attribute__((ext_vector_type(4))) float f32x4;

__device__ __forceinline__ ushort f2bf(float f) {
  unsigned int x = __float_as_uint(f);
  unsigned int r = (x + 0x7fffu + ((x >> 16) & 1u)) >> 16;  // RNE
  return (ushort)r;
}

// exact tanh-gelu, rearranged: 0.5x(1+tanh(z)) = x*e^{2z}/(e^{2z}+1)
__device__ __forceinline__ float gelu_fast(float x) {
  float x2 = x * x;
  float t = __builtin_fmaf(x2, 0.044715f, 1.0f);
  float m = x * t * 2.3025851f;
  m = fminf(m, 126.0f);
  float p = __builtin_amdgcn_exp2f(m);
  return x * p * __builtin_amdgcn_rcpf(p + 1.0f);
}

__device__ __forceinline__ void async_copy16(const void* gsrc, void* ldst) {
  __builtin_amdgcn_global_load_lds(
      (const __attribute__((address_space(1))) void*)gsrc,
      (__attribute__((address_space(3))) void*)ldst, 16, 0, 0);
}

// ---------------- fused pre-pass: ONE kernel, three independent block ranges ----------------
//   b < 16384 : streaming cast w1 -> w1b, w2 -> w2b (bf16, SAME layout — no transpose)
//   b < 18432 : gating + inp->bf16 (atomic append to per-expert lists)
//   b < 20480 : zero y (gemm2 accumulates into y with atomics)
// The r6 64x64-tile transpose was stuck at 288us / 1.17 TB/s regardless of LDS fixes
// (scattered-side access structure). The cast is unit-stride both sides; the GEMMs now
// rebuild B^T in LDS themselves via register staging.
__global__ __launch_bounds__(256) void fused_pre_kernel(
    const float* __restrict__ w1, const float* __restrict__ w2,
    ushort* __restrict__ w1b, ushort* __restrict__ w2b,
    const float* __restrict__ inp, const float* __restrict__ gw,
    const float* __restrict__ gb, ushort* __restrict__ inp_bf,
    int* __restrict__ counts, int* __restrict__ tok_list,
    float* __restrict__ scale_list, float* __restrict__ y) {
  const int b = blockIdx.x;

  if (b < 16384) {
    const float* src;
    ushort* dst;
    if (b < 8192) { src = w1 + (size_t)b * 4096; dst = w1b + (size_t)b * 4096; }
    else          { src = w2 + (size_t)(b - 8192) * 4096; dst = w2b + (size_t)(b - 8192) * 4096; }
    const float4* s4 = (const float4*)src;
    ushort4* d4 = (ushort4*)dst;
    const int t = threadIdx.x;
#pragma unroll
    for (int j = 0; j < 4; j++) {
      float4 v = s4[t + j * 256];
      ushort4 o = { f2bf(v.x), f2bf(v.y), f2bf(v.z), f2bf(v.w) };
      d4[t + j * 256] = o;
    }
  } else if (b < 18432) {
    // ---- gating part: one wave per token ----
    const int wave = threadIdx.x >> 6, lane = threadIdx.x & 63;
    const int token = (b - 16384) * 4 + wave;
    const float* x = inp + (size_t)token * DM;
    ushort* xb = inp_bf + (size_t)token * DM;
    float acc[NE];
#pragma unroll
    for (int e = 0; e < NE; e++) acc[e] = 0.f;
#pragma unroll
    for (int j = 0; j < 16; j++) {
      int idx = j * 64 + lane;
      float xv = x[idx];
      xb[idx] = f2bf(xv);
      const float4* g = (const float4*)(gw + (size_t)idx * NE);
      float4 g0 = g[0], g1 = g[1];
      acc[0] += xv * g0.x; acc[1] += xv * g0.y; acc[2] += xv * g0.z; acc[3] += xv * g0.w;
      acc[4] += xv * g1.x; acc[5] += xv * g1.y; acc[6] += xv * g1.z; acc[7] += xv * g1.w;
    }
#pragma unroll
    for (int e = 0; e < NE; e++) {
      for (int off = 32; off; off >>= 1) acc[e] += __shfl_xor(acc[e], off, 64);
    }
    if (lane == 0) {
      float v[NE];
#pragma unroll
      for (int e = 0; e < NE; e++) v[e] = acc[e] + gb[e];
      int i0 = 0; float b0 = v[0];
#pragma unroll
      for (int e = 1; e < NE; e++) if (v[e] > b0) { b0 = v[e]; i0 = e; }
      int i1 = -1; float b1v = -INFINITY;
#pragma unroll
      for (int e = 0; e < NE; e++) if (e != i0 && v[e] > b1v) { b1v = v[e]; i1 = e; }
      float s1 = 1.f / (1.f + __expf(b0 - b1v));  // softmax over the two selected logits
      float s0 = 1.f - s1;
      int p0 = atomicAdd(&counts[i0], 1);
      tok_list[i0 * NT + p0] = token;
      scale_list[i0 * NT + p0] = s0;
      int p1 = atomicAdd(&counts[i1], 1);
      tok_list[i1 * NT + p1] = token;
      scale_list[i1 * NT + p1] = s1;
    }
  } else {
    // ---- y-zero part: 2048 blocks x 4096 floats ----
    const int idx = b - 18432;
    float4* dst = (float4*)(y + (size_t)idx * 4096);
    f32x4 z = {0.f, 0.f, 0.f, 0.f};
#pragma unroll
    for (int j = 0; j < 4; j++)
      ((f32x4*)dst)[j * 256 + threadIdx.x] = z;
  }
}

// GEMM skeleton: 128x128 tile, 256 thr (4 waves 2x2), counted-vmcnt 3-buffer pipeline.
// A: [128m][32k] bf16 via global_load_lds, chunk-XOR swizzled source (r2-verified).
// B: weights are row-major [K][N]; each K-step the block REBUILDS the r2-verified
// B^T LDS layout ([128n][32k], chunk-XOR swizzle) via register staging:
//   thread t: br = t&15 (row pair k=2br,2br+1), bg = t>>4 (cols n=8bg..+7);
//   2x global_load_dwordx4 (waves cover whole 64B lines -> coalesced);
//   pack dword(n) = W[2br][n] | W[2br+1][n]<<16; 8x ds_write_b32 at
//   byte = n*64 + ((br>>2)^((n>>1)&3))*16 + (br&3)*4  (matches read swizzle).
// Stage = 2 A-gloads + 2 B-reg-loads = 4 VMEM/wave in order -> vmcnt(4) at top of
// step completes tile t's set (identical accounting to verified r2). B-writes land
// pre-barrier (+lgkmcnt(0)); the compute path is byte-identical to r2 (conflicts=0).

#define STAGE_A(base)                                      \
  do {                                                     \
    async_copy16(aP0, (char*)(base) + wv * 1024);          \
    async_copy16(aP1, (char*)(base) + 4096 + wv * 1024);   \
    aP0 += 32; aP1 += 32;                                  \
  } while (0)

#define LOAD_B(ra, rb, LDB)                                \
  do {                                                     \
    ra = *(const uint4*)(bSrc);                            \
    rb = *(const uint4*)(bSrc + (LDB));                    \
    bSrc += (size_t)32 * (LDB);                            \
  } while (0)

#define WRITE_B(Breg, ra, rb)                                                  \
  do {                                                                         \
    uint d0 = (ra.x & 0xffffu) | (rb.x << 16);                                 \
    uint d1 = (ra.x >> 16)     | (rb.x & 0xffff0000u);                         \
    uint d2 = (ra.y & 0xffffu) | (rb.y << 16);                                 \
    uint d3 = (ra.y >> 16)     | (rb.y & 0xffff0000u);                         \
    uint d4 = (ra.z & 0xffffu) | (rb.z << 16);                                 \
    uint d5 = (ra.z >> 16)     | (rb.z & 0xffff0000u);                         \
    uint d6 = (ra.w & 0xffffu) | (rb.w << 16);                                 \
    uint d7 = (ra.w >> 16)     | (rb.w & 0xffff0000u);                         \
    char* bb = (char*)(Breg) + wbBase;                                         \
    *(uint*)(bb + wbOff0) = d0;  *(uint*)(bb + wbOff0 + 64) = d1;              \
    *(uint*)(bb + wbOff1) = d2;  *(uint*)(bb + wbOff1 + 64) = d3;              \
    *(uint*)(bb + wbOff2) = d4;  *(uint*)(bb + wbOff2 + 64) = d5;              \
    *(uint*)(bb + wbOff3) = d6;  *(uint*)(bb + wbOff3 + 64) = d7;              \
  } while (0)

// ---------------- GEMM1: h[off_e+gi] = gelu(x[tok] @ w1[e] + b1[e]), bf16 dense ----------------
__global__ __launch_bounds__(256) void gemm1_kernel(
    const ushort* __restrict__ xbf, const ushort* __restrict__ w1b,
    const float* __restrict__ b1, const int* __restrict__ tok_list,
    const int* __restrict__ counts, ushort* __restrict__ hbuf) {
  const int b = blockIdx.x;
  const int e = b & 7;
  const int idx = b >> 3;        // 0..2047
  const int mTile = idx & 63;    // fastest
  const int nTile = idx >> 6;    // 0..31
  int off = 0;
  for (int i = 0; i < e; i++) off += counts[i];
  const int cnt = counts[e];
  if (mTile * 128 >= cnt) return;

  __shared__ __attribute__((aligned(128))) char ldsB[49152];  // 3 x (A 8KB + B 8KB)

  const int t = threadIdx.x;
  const int lane = t & 63, wv = t >> 6;
  const int wm = wv & 1, wn = wv >> 1;

  // A staging (unchanged from r2, swizzled source chunk)
  const int sr = t >> 2;
  const int sc = (((t & 3) ^ ((sr >> 1) & 3)) * 8);
  int gi0 = mTile * 128 + sr;      if (gi0 >= cnt) gi0 = cnt - 1;
  int gi1 = mTile * 128 + 64 + sr; if (gi1 >= cnt) gi1 = cnt - 1;
  const int tok0 = tok_list[e * NT + gi0];
  const int tok1 = tok_list[e * NT + gi1];
  const ushort* aP0 = xbf + (size_t)tok0 * DM + sc;
  const ushort* aP1 = xbf + (size_t)tok1 * DM + sc;

  // B register staging setup
  const int br = t & 15;     // row-pair index (k = 2br, 2br+1)
  const int bg = t >> 4;     // col block (n = 8bg..8bg+7)
  const ushort* bSrc = w1b + (size_t)e * DM * DH + (size_t)(2 * br) * DH + nTile * 128 + bg * 8;
  const int wbBase = 512 * bg + 4 * (br & 3);
  const int s_ = br >> 2;
  const int wbOff0 = 16 * (s_ ^ 0) + 0;
  const int wbOff1 = 16 * (s_ ^ 1) + 128;
  const int wbOff2 = 16 * (s_ ^ 2) + 256;
  const int wbOff3 = 16 * (s_ ^ 3) + 384;
  uint4 raA, rbA, raB, rbB;

  f32x4 zero = {0.f, 0.f, 0.f, 0.f};
  f32x4 acc[4][4];
#pragma unroll
  for (int i = 0; i < 4; i++)
#pragma unroll
    for (int j = 0; j < 4; j++) acc[i][j] = zero;

  const int quad = lane >> 4, lc = lane & 15;
  const int rq = quad ^ ((lc >> 1) & 3);          // swizzled chunk for reads

  auto compute = [&](const char* buf) {
    const char* A_ = buf;
    const char* B_ = buf + 8192;
    bf16x8 af[4], bfr[4];
#pragma unroll
    for (int mi = 0; mi < 4; mi++) {
      int row = wm * 64 + mi * 16 + lc;
      af[mi] = *(const bf16x8*)(A_ + row * 64 + rq * 16);
    }
#pragma unroll
    for (int ni = 0; ni < 4; ni++) {
      int row = wn * 64 + ni * 16 + lc;
      bfr[ni] = *(const bf16x8*)(B_ + row * 64 + rq * 16);
    }
#pragma unroll
    for (int mi = 0; mi < 4; mi++)
#pragma unroll
      for (int ni = 0; ni < 4; ni++)
        acc[mi][ni] = __builtin_amdgcn_mfma_f32_16x16x32_bf16(af[mi], bfr[ni], acc[mi][ni], 0, 0, 0);
  };

  const int NIT = DM / 32;  // 32 (even)
  // prologue: stage tiles 0 (set A) and 1 (set B): 8 VMEM outstanding
  STAGE_A(ldsB);           LOAD_B(raA, rbA, DH);
  STAGE_A(ldsB + 16384);   LOAD_B(raB, rbB, DH);
  int cur = 0;
  for (int tt = 0; tt < NIT - 2; tt += 2) {
    // even step: set A
    asm volatile("s_waitcnt vmcnt(4)" ::: "memory");   // tile tt: A in LDS, B in regs
    WRITE_B(ldsB + cur * 16384 + 8192, raA, rbA);
    asm volatile("s_waitcnt lgkmcnt(0)" ::: "memory");
    __builtin_amdgcn_s_barrier();                       // buf(tt) complete everywhere
    { int nx = cur + 2; if (nx >= 3) nx -= 3;
      STAGE_A(ldsB + nx * 16384);  LOAD_B(raA, rbA, DH); }
    compute(ldsB + cur * 16384);
    cur = (cur == 2) ? 0 : cur + 1;
    // odd step: set B
    asm volatile("s_waitcnt vmcnt(4)" ::: "memory");
    WRITE_B(ldsB + cur * 16384 + 8192, raB, rbB);
    asm volatile("s_waitcnt lgkmcnt(0)" ::: "memory");
    __builtin_amdgcn_s_barrier();
    { int nx = cur + 2; if (nx >= 3) nx -= 3;
      STAGE_A(ldsB + nx * 16384);  LOAD_B(raB, rbB, DH); }
    compute(ldsB + cur * 16384);
    cur = (cur == 2) ? 0 : cur + 1;
  }
  // step NIT-2 (set A), no staging
  asm volatile("s_waitcnt vmcnt(4)" ::: "memory");
  WRITE_B(ldsB + cur * 16384 + 8192, raA, rbA);
  asm volatile("s_waitcnt lgkmcnt(0)" ::: "memory");
  __builtin_amdgcn_s_barrier();
  compute(ldsB + cur * 16384);
  cur = (cur == 2) ? 0 : cur + 1;
  // step NIT-1 (set B)
  asm volatile("s_waitcnt vmcnt(0)" ::: "memory");
  WRITE_B(ldsB + cur * 16384 + 8192, raB, rbB);
  asm volatile("s_waitcnt lgkmcnt(0)" ::: "memory");
  __builtin_amdgcn_s_barrier();
  compute(ldsB + cur * 16384);

  float bias[4];
#pragma unroll
  for (int ni = 0; ni < 4; ni++)
    bias[ni] = b1[(size_t)e * DH + nTile * 128 + wn * 64 + ni * 16 + lc];

#pragma unroll
  for (int mi = 0; mi < 4; mi++) {
#pragma unroll
    for (int r = 0; r < 4; r++) {
      int lr = wm * 64 + mi * 16 + quad * 4 + r;
      int gi = mTile * 128 + lr;
      if (gi < cnt) {
        ushort* hrow = hbuf + (size_t)(off + gi) * DH + nTile * 128 + wn * 64 + lc;
#pragma unroll
        for (int ni = 0; ni < 4; ni++) {
          float v = acc[mi][ni][r] + bias[ni];
          hrow[ni * 16] = f2bf(gelu_fast(v));
        }
      }
    }
  }
}

// ---------------- GEMM2 (fused combine): y[tok] += s * (h @ w2[e] + b2[e]) ----------------
__global__ __launch_bounds__(256) void gemm2_kernel(
    const ushort* __restrict__ hbuf, const ushort* __restrict__ w2b,
    const float* __restrict__ b2, const int* __restrict__ tok_list,
    const float* __restrict__ scale_list, const int* __restrict__ counts,
    float* __restrict__ y) {
  const int b = blockIdx.x;
  const int e = b & 7;               // XCD pin
  const int idx = b >> 3;            // 0..511
  const int nTile = idx & 7;         // fastest: hbuf A-panel reuse
  const int mTile = idx >> 3;        // 0..63
  int off = 0;
  for (int i = 0; i < e; i++) off += counts[i];
  const int cnt = counts[e];
  if (mTile * 128 >= cnt) return;

  __shared__ __attribute__((aligned(128))) char ldsB[49152];  // 3 x (A 8KB + B 8KB)

  const int t = threadIdx.x;
  const int lane = t & 63, wv = t >> 6;
  const int wm = wv & 1, wn = wv >> 1;

  const int sr = t >> 2;
  const int sc = (((t & 3) ^ ((sr >> 1) & 3)) * 8);
  int gi0 = mTile * 128 + sr;      if (gi0 >= cnt) gi0 = cnt - 1;
  int gi1 = mTile * 128 + 64 + sr; if (gi1 >= cnt) gi1 = cnt - 1;
  const ushort* aP0 = hbuf + (size_t)(off + gi0) * DH + sc;
  const ushort* aP1 = hbuf + (size_t)(off + gi1) * DH + sc;

  const int br = t & 15;
  const int bg = t >> 4;
  const ushort* bSrc = w2b + (size_t)e * DH * DM + (size_t)(2 * br) * DM + nTile * 128 + bg * 8;
  const int wbBase = 512 * bg + 4 * (br & 3);
  const int s_ = br >> 2;
  const int wbOff0 = 16 * (s_ ^ 0) + 0;
  const int wbOff1 = 16 * (s_ ^ 1) + 128;
  const int wbOff2 = 16 * (s_ ^ 2) + 256;
  const int wbOff3 = 16 * (s_ ^ 3) + 384;
  uint4 raA, rbA, raB, rbB;

  f32x4 zero = {0.f, 0.f, 0.f, 0.f};
  f32x4 acc[4][4];
#pragma unroll
  for (int i = 0; i < 4; i++)
#pragma unroll
    for (int j = 0; j < 4; j++) acc[i][j] = zero;

  const int quad = lane >> 4, lc = lane & 15;
  const int rq = quad ^ ((lc >> 1) & 3);

  auto compute = [&](const char* buf) {
    const char* A_ = buf;
    const char* B_ = buf + 8192;
    bf16x8 af[4], bfr[4];
#pragma unroll
    for (int mi = 0; mi < 4; mi++) {
      int row = wm * 64 + mi * 16 + lc;
      af[mi] = *(const bf16x8*)(A_ + row * 64 + rq * 16);
    }
#pragma unroll
    for (int ni = 0; ni < 4; ni++) {
      int row = wn * 64 + ni * 16 + lc;
      bfr[ni] = *(const bf16x8*)(B_ + row * 64 + rq * 16);
    }
#pragma unroll
    for (int mi = 0; mi < 4; mi++)
#pragma unroll
      for (int ni = 0; ni < 4; ni++)
        acc[mi][ni] = __builtin_amdgcn_mfma_f32_16x16x32_bf16(af[mi], bfr[ni], acc[mi][ni], 0, 0, 0);
  };

  const int NIT = DH / 32;  // 128 (even)
  STAGE_A(ldsB);           LOAD_B(raA, rbA, DM);
  STAGE_A(ldsB + 16384);   LOAD_B(raB, rbB, DM);
  int cur = 0;
  for (int tt = 0; tt < NIT - 2; tt += 2) {
    asm volatile("s_waitcnt vmcnt(4)" ::: "memory");
    WRITE_B(ldsB + cur * 16384 + 8192, raA, rbA);
    asm volatile("s_waitcnt lgkmcnt(0)" ::: "memory");
    __builtin_amdgcn_s_barrier();
    { int nx = cur + 2; if (nx >= 3) nx -= 3;
      STAGE_A(ldsB + nx * 16384);  LOAD_B(raA, rbA, DM); }
    compute(ldsB + cur * 16384);
    cur = (cur == 2) ? 0 : cur + 1;
    asm volatile("s_waitcnt vmcnt(4)" ::: "memory");
    WRITE_B(ldsB + cur * 16384 + 8192, raB, rbB);
    asm volatile("s_waitcnt lgkmcnt(0)" ::: "memory");
    __builtin_amdgcn_s_barrier();
    { int nx = cur + 2; if (nx >= 3) nx -= 3;
      STAGE_A(ldsB + nx * 16384);  LOAD_B(raB, rbB, DM); }
    compute(ldsB + cur * 16384);
    cur = (cur == 2) ? 0 : cur + 1;
  }
  asm volatile("s_waitcnt vmcnt(4)" ::: "memory");
  WRITE_B(ldsB + cur * 16384 + 8192, raA, rbA);
  asm volatile("s_waitcnt lgkmcnt(0)" ::: "memory");
  __builtin_amdgcn_s_barrier();
  compute(ldsB + cur * 16384);
  cur = (cur == 2) ? 0 : cur + 1;
  asm volatile("s_waitcnt vmcnt(0)" ::: "memory");
  WRITE_B(ldsB + cur * 16384 + 8192, raB, rbB);
  asm volatile("s_waitcnt lgkmcnt(0)" ::: "memory");
  __builtin_amdgcn_s_barrier();
  compute(ldsB + cur * 16384);

  float bias[4];
#pragma unroll
  for (int ni = 0; ni < 4; ni++)
    bias[ni] = b2[(size_t)e * DM + nTile * 128 + wn * 64 + ni * 16 + lc];

#pragma unroll
  for (int mi = 0; mi < 4; mi++) {
#pragma unroll
    for (int r = 0; r < 4; r++) {
      int lr = wm * 64 + mi * 16 + quad * 4 + r;
      int gi = mTile * 128 + lr;
      if (gi < cnt) {
        int tok = tok_list[e * NT + gi];
        float s = scale_list[e * NT + gi];
        float* yrow = y + (size_t)tok * DM + nTile * 128 + wn * 64 + lc;
#pragma unroll
        for (int ni = 0; ni < 4; ni++) {
          float v = (acc[mi][ni][r] + bias[ni]) * s;
          unsafeAtomicAdd(&yrow[ni * 16], v);
        }
      }
    }
  }
}

extern "C" void kernel_launch(void* const* d_in, const int* in_sizes, int n_in,
                              void* d_out, int out_size, void* d_ws, size_t ws_size,
                              hipStream_t stream) {
  const float* inp = (const float*)d_in[0];
  const float* gw  = (const float*)d_in[1];
  const float* gb  = (const float*)d_in[2];
  const float* w1  = (const float*)d_in[3];
  const float* b1  = (const float*)d_in[4];
  const float* w2  = (const float*)d_in[5];
  const float* b2  = (const float*)d_in[6];
  float* y = (float*)d_out;

  // workspace layout (~286 MB total)
  char* ws = (char*)d_ws;
  ushort* inp_bf = (ushort*)ws;              ws += (size_t)NT * DM * 2;
  ushort* w1b    = (ushort*)ws;              ws += (size_t)NE * DM * DH * 2;
  ushort* w2b    = (ushort*)ws;              ws += (size_t)NE * DH * DM * 2;
  ushort* hbuf   = (ushort*)ws;              ws += (size_t)NP * DH * 2;
  int*    tok_list   = (int*)ws;             ws += (size_t)NE * NT * 4;
  float*  scale_list = (float*)ws;           ws += (size_t)NE * NT * 4;
  int*    counts     = (int*)ws;             ws += 256;

  hipMemsetAsync(counts, 0, 256, stream);

  // node 2: weight cast (16384 blocks) + gate (2048) + y-zero (2048), fused
  fused_pre_kernel<<<20480, 256, 0, stream>>>(w1, w2, w1b, w2b, inp, gw, gb,
                                              inp_bf, counts, tok_list, scale_list, y);
  // node 3: GEMM1 (128^2, 3-buffer counted-vmcnt; B^T rebuilt in LDS via reg staging)
  gemm1_kernel<<<NE * 32 * 64, 256, 0, stream>>>(inp_bf, w1b, b1, tok_list, counts, hbuf);
  // node 4: GEMM2 with fused scale+combine via atomics into y
  gemm2_kernel<<<NE * 8 * 64, 256, 0, stream>>>(hbuf, w2b, b2, tok_list, scale_list, counts, y);
}

// Round 9
// 904.945 us; speedup vs baseline: 1.2446x; 1.2446x over previous
//
#include <hip/hip_runtime.h>
#include <hip/hip_bf16.h>

#define NT 8192      // tokens
#define DM 1024      // d_model
#define NE 8         // experts
#define DH 4096      // d_hidden
#define NP (NT * 2)  // token-expert pairs (TOP_K = 2)

typedef __attribute__((ext_vector_type(8))) __bf16 bf16x8;
typedef __attribute__((ext_vector_type(4))) float f32x4;

__device__ __forceinline__ ushort f2bf(float f) {
  unsigned int x = __float_as_uint(f);
  unsigned int r = (x + 0x7fffu + ((x >> 16) & 1u)) >> 16;  // RNE
  return (ushort)r;
}

// exact tanh-gelu, rearranged: 0.5x(1+tanh(z)) = x*e^{2z}/(e^{2z}+1)
__device__ __forceinline__ float gelu_fast(float x) {
  float x2 = x * x;
  float t = __builtin_fmaf(x2, 0.044715f, 1.0f);
  float m = x * t * 2.3025851f;
  m = fminf(m, 126.0f);
  float p = __builtin_amdgcn_exp2f(m);
  return x * p * __builtin_amdgcn_rcpf(p + 1.0f);
}

__device__ __forceinline__ void async_copy16(const void* gsrc, void* ldst) {
  __builtin_amdgcn_global_load_lds(
      (const __attribute__((address_space(1))) void*)gsrc,
      (__attribute__((address_space(3))) void*)ldst, 16, 0, 0);
}

// ---------------- fused pre-pass: ONE kernel, three independent block ranges ----------------
//   b < 4096 : weight transpose+cvt (w1 -> w1t, w2 -> w2t), 128x128 tiles
//   b < 6144 : gating + inp->bf16 (atomic append to per-expert lists)
//   b < 8192 : zero y (gemm2 accumulates into y with atomics)
// Transpose redesign (r6 was DRAM-page-locality bound at 1.17 TB/s with 256B-read /
// 128B-write segments): 128x128 tiles double both segment sizes (512B reads, 256B
// writes), register 4x4 micro-transpose, LDS 34.8KB. Row-tile index fastest so
// co-resident blocks share column panels.
__global__ __launch_bounds__(256) void fused_pre_kernel(
    const float* __restrict__ w1, const float* __restrict__ w2,
    ushort* __restrict__ w1t, ushort* __restrict__ w2t,
    const float* __restrict__ inp, const float* __restrict__ gw,
    const float* __restrict__ gb, ushort* __restrict__ inp_bf,
    int* __restrict__ counts, int* __restrict__ tok_list,
    float* __restrict__ scale_list, float* __restrict__ y) {
  __shared__ ushort tileT[128][136];   // [n][k], pad 136 (transpose branch only)
  const int b = blockIdx.x;

  if (b < 4096) {
    // ---- transpose part: 128x128 tile ----
    const int which = b >> 11;         // 0 = w1, 1 = w2
    const int rem = b & 2047;
    const int e = rem >> 8;            // expert
    const int bb = rem & 255;          // 256 tiles per expert-weight
    const float* src;
    ushort* dst;
    int R, C, r0, c0;
    if (which == 0) {
      src = w1 + (size_t)e * DM * DH; dst = w1t + (size_t)e * DM * DH;
      R = DM; C = DH;
      r0 = (bb & 7) * 128;   c0 = (bb >> 3) * 128;   // 8 row-tiles x 32 col-tiles
    } else {
      src = w2 + (size_t)e * DM * DH; dst = w2t + (size_t)e * DM * DH;
      R = DH; C = DM;
      r0 = (bb & 31) * 128;  c0 = (bb >> 5) * 128;   // 32 row-tiles x 8 col-tiles
    }
    const int tx = threadIdx.x & 31;   // col group (4 cols)
    const int ty = threadIdx.x >> 5;   // 0..7
    // phase 1: 4x4 register micro-transpose blocks; reads are 512B/row segments
#pragma unroll
    for (int i = 0; i < 4; i++) {
      int rb = ty + 8 * i;             // 4-row block 0..31
      const float* sp = src + (size_t)(r0 + 4 * rb) * C + c0 + 4 * tx;
      float4 a0 = *(const float4*)(sp);
      float4 a1 = *(const float4*)(sp + C);
      float4 a2 = *(const float4*)(sp + 2 * (size_t)C);
      float4 a3 = *(const float4*)(sp + 3 * (size_t)C);
      ushort4 o0 = { f2bf(a0.x), f2bf(a1.x), f2bf(a2.x), f2bf(a3.x) };
      ushort4 o1 = { f2bf(a0.y), f2bf(a1.y), f2bf(a2.y), f2bf(a3.y) };
      ushort4 o2 = { f2bf(a0.z), f2bf(a1.z), f2bf(a2.z), f2bf(a3.z) };
      ushort4 o3 = { f2bf(a0.w), f2bf(a1.w), f2bf(a2.w), f2bf(a3.w) };
      *(ushort4*)(&tileT[4 * tx + 0][4 * rb]) = o0;
      *(ushort4*)(&tileT[4 * tx + 1][4 * rb]) = o1;
      *(ushort4*)(&tileT[4 * tx + 2][4 * rb]) = o2;
      *(ushort4*)(&tileT[4 * tx + 3][4 * rb]) = o3;
    }
    __syncthreads();
    // phase 2: 256B-contiguous dst segments (32 lanes x 8B)
    const int kx = threadIdx.x & 31;   // k chunk (4 ushorts)
    const int ny = threadIdx.x >> 5;   // 0..7
#pragma unroll
    for (int i = 0; i < 16; i++) {
      int n = ny + 8 * i;              // 0..127
      *(ushort4*)(dst + (size_t)(c0 + n) * R + r0 + 4 * kx) =
          *(const ushort4*)(&tileT[n][4 * kx]);
    }
  } else if (b < 6144) {
    // ---- gating part: one wave per token ----
    const int wave = threadIdx.x >> 6, lane = threadIdx.x & 63;
    const int token = (b - 4096) * 4 + wave;
    const float* x = inp + (size_t)token * DM;
    ushort* xb = inp_bf + (size_t)token * DM;
    float acc[NE];
#pragma unroll
    for (int e = 0; e < NE; e++) acc[e] = 0.f;
#pragma unroll
    for (int j = 0; j < 16; j++) {
      int idx = j * 64 + lane;
      float xv = x[idx];
      xb[idx] = f2bf(xv);
      const float4* g = (const float4*)(gw + (size_t)idx * NE);
      float4 g0 = g[0], g1 = g[1];
      acc[0] += xv * g0.x; acc[1] += xv * g0.y; acc[2] += xv * g0.z; acc[3] += xv * g0.w;
      acc[4] += xv * g1.x; acc[5] += xv * g1.y; acc[6] += xv * g1.z; acc[7] += xv * g1.w;
    }
#pragma unroll
    for (int e = 0; e < NE; e++) {
      for (int off = 32; off; off >>= 1) acc[e] += __shfl_xor(acc[e], off, 64);
    }
    if (lane == 0) {
      float v[NE];
#pragma unroll
      for (int e = 0; e < NE; e++) v[e] = acc[e] + gb[e];
      int i0 = 0; float b0 = v[0];
#pragma unroll
      for (int e = 1; e < NE; e++) if (v[e] > b0) { b0 = v[e]; i0 = e; }
      int i1 = -1; float b1v = -INFINITY;
#pragma unroll
      for (int e = 0; e < NE; e++) if (e != i0 && v[e] > b1v) { b1v = v[e]; i1 = e; }
      float s1 = 1.f / (1.f + __expf(b0 - b1v));  // softmax over the two selected logits
      float s0 = 1.f - s1;
      int p0 = atomicAdd(&counts[i0], 1);
      tok_list[i0 * NT + p0] = token;
      scale_list[i0 * NT + p0] = s0;
      int p1 = atomicAdd(&counts[i1], 1);
      tok_list[i1 * NT + p1] = token;
      scale_list[i1 * NT + p1] = s1;
    }
  } else {
    // ---- y-zero part: 2048 blocks x 4096 floats ----
    const int idx = b - 6144;
    float4* dst = (float4*)(y + (size_t)idx * 4096);
    f32x4 z = {0.f, 0.f, 0.f, 0.f};
#pragma unroll
    for (int j = 0; j < 4; j++)
      ((f32x4*)dst)[j * 256 + threadIdx.x] = z;
  }
}

// GEMM skeleton (round-5 verified champion): 128x128 tile, 256 thr (4 waves, 2x2),
// counted-vmcnt 3-buffer pipeline (T3/T4) + chunk-XOR LDS swizzle (T2, both-sides).
// Buffer = 16 KB: A[128][32]bf16 then B[128][32]bf16; within each 64B row the four
// 16B chunks sit at chunk^((row>>1)&3). 3 buffers = 48 KB.
// Each wave issues exactly 4 loads per stage -> vmcnt(4) completes the oldest stage.

#define STAGE_TILE(base)                                      \
  do {                                                        \
    async_copy16(aP0, (char*)(base) + wv * 1024);             \
    async_copy16(aP1, (char*)(base) + 4096 + wv * 1024);      \
    async_copy16(bP0, (char*)(base) + 8192 + wv * 1024);      \
    async_copy16(bP1, (char*)(base) + 12288 + wv * 1024);     \
    aP0 += 32; aP1 += 32; bP0 += 32; bP1 += 32;               \
  } while (0)

// ---------------- GEMM1: h[off_e+gi] = gelu(x[tok] @ w1[e] + b1[e]), bf16 dense ----------------
__global__ __launch_bounds__(256) void gemm1_kernel(
    const ushort* __restrict__ xbf, const ushort* __restrict__ w1t,
    const float* __restrict__ b1, const int* __restrict__ tok_list,
    const int* __restrict__ counts, ushort* __restrict__ hbuf) {
  const int b = blockIdx.x;
  const int e = b & 7;
  const int idx = b >> 3;        // 0..2047
  const int mTile = idx & 63;    // fastest
  const int nTile = idx >> 6;    // 0..31
  int off = 0;
  for (int i = 0; i < e; i++) off += counts[i];
  const int cnt = counts[e];
  if (mTile * 128 >= cnt) return;

  __shared__ __attribute__((aligned(128))) char ldsB[49152];  // 3 x (A 8KB + B 8KB)

  const int t = threadIdx.x;
  const int lane = t & 63, wv = t >> 6;
  const int wm = wv & 1, wn = wv >> 1;

  const int sr = t >> 2;                             // staging row 0..63
  const int sc = (((t & 3) ^ ((sr >> 1) & 3)) * 8);  // swizzled source chunk (ushorts)
  int gi0 = mTile * 128 + sr;      if (gi0 >= cnt) gi0 = cnt - 1;
  int gi1 = mTile * 128 + 64 + sr; if (gi1 >= cnt) gi1 = cnt - 1;
  const int tok0 = tok_list[e * NT + gi0];
  const int tok1 = tok_list[e * NT + gi1];
  const ushort* aP0 = xbf + (size_t)tok0 * DM + sc;
  const ushort* aP1 = xbf + (size_t)tok1 * DM + sc;
  const ushort* bP0 = w1t + ((size_t)e * DH + nTile * 128 + sr) * DM + sc;
  const ushort* bP1 = bP0 + (size_t)64 * DM;

  f32x4 zero = {0.f, 0.f, 0.f, 0.f};
  f32x4 acc[4][4];
#pragma unroll
  for (int i = 0; i < 4; i++)
#pragma unroll
    for (int j = 0; j < 4; j++) acc[i][j] = zero;

  const int quad = lane >> 4, lc = lane & 15;
  const int rq = quad ^ ((lc >> 1) & 3);          // swizzled chunk for reads

  auto compute = [&](const char* buf) {
    const char* A_ = buf;
    const char* B_ = buf + 8192;
    bf16x8 af[4], bfr[4];
#pragma unroll
    for (int mi = 0; mi < 4; mi++) {
      int row = wm * 64 + mi * 16 + lc;
      af[mi] = *(const bf16x8*)(A_ + row * 64 + rq * 16);
    }
#pragma unroll
    for (int ni = 0; ni < 4; ni++) {
      int row = wn * 64 + ni * 16 + lc;
      bfr[ni] = *(const bf16x8*)(B_ + row * 64 + rq * 16);
    }
#pragma unroll
    for (int mi = 0; mi < 4; mi++)
#pragma unroll
      for (int ni = 0; ni < 4; ni++)
        acc[mi][ni] = __builtin_amdgcn_mfma_f32_16x16x32_bf16(af[mi], bfr[ni], acc[mi][ni], 0, 0, 0);
  };

  const int NIT = DM / 32;  // 32
  STAGE_TILE(ldsB);
  STAGE_TILE(ldsB + 16384);
  int cur = 0;
  for (int tt = 0; tt < NIT - 1; ++tt) {
    // outstanding = stage(tt)+stage(tt+1) = 8; complete the oldest 4 = stage(tt)
    asm volatile("s_waitcnt vmcnt(4)" ::: "memory");
    __builtin_amdgcn_s_barrier();   // buf(tt) fully staged; all waves done reading buf(tt-1)
    if (tt + 2 < NIT) {
      int nx = cur + 2; if (nx >= 3) nx -= 3;
      STAGE_TILE(ldsB + nx * 16384);
    }
    compute(ldsB + cur * 16384);
    cur = (cur == 2) ? 0 : cur + 1;
  }
  asm volatile("s_waitcnt vmcnt(0)" ::: "memory");
  __builtin_amdgcn_s_barrier();
  compute(ldsB + cur * 16384);

  float bias[4];
#pragma unroll
  for (int ni = 0; ni < 4; ni++)
    bias[ni] = b1[(size_t)e * DH + nTile * 128 + wn * 64 + ni * 16 + lc];

#pragma unroll
  for (int mi = 0; mi < 4; mi++) {
#pragma unroll
    for (int r = 0; r < 4; r++) {
      int lr = wm * 64 + mi * 16 + quad * 4 + r;
      int gi = mTile * 128 + lr;
      if (gi < cnt) {
        ushort* hrow = hbuf + (size_t)(off + gi) * DH + nTile * 128 + wn * 64 + lc;
#pragma unroll
        for (int ni = 0; ni < 4; ni++) {
          float v = acc[mi][ni][r] + bias[ni];
          hrow[ni * 16] = f2bf(gelu_fast(v));
        }
      }
    }
  }
}

// ---------------- GEMM2 (fused combine): y[tok] += s * (h @ w2[e] + b2[e]) ----------------
// No split-K: atomics only resolve the 2-expert-per-token accumulation into y.
__global__ __launch_bounds__(256) void gemm2_kernel(
    const ushort* __restrict__ hbuf, const ushort* __restrict__ w2t,
    const float* __restrict__ b2, const int* __restrict__ tok_list,
    const float* __restrict__ scale_list, const int* __restrict__ counts,
    float* __restrict__ y) {
  const int b = blockIdx.x;
  const int e = b & 7;               // XCD pin
  const int idx = b >> 3;            // 0..511
  const int nTile = idx & 7;         // fastest: hbuf A-panel reuse
  const int mTile = idx >> 3;        // 0..63
  int off = 0;
  for (int i = 0; i < e; i++) off += counts[i];
  const int cnt = counts[e];
  if (mTile * 128 >= cnt) return;

  __shared__ __attribute__((aligned(128))) char ldsB[49152];  // 3 x (A 8KB + B 8KB)

  const int t = threadIdx.x;
  const int lane = t & 63, wv = t >> 6;
  const int wm = wv & 1, wn = wv >> 1;

  const int sr = t >> 2;
  const int sc = (((t & 3) ^ ((sr >> 1) & 3)) * 8);  // swizzled source chunk (ushorts)
  int gi0 = mTile * 128 + sr;      if (gi0 >= cnt) gi0 = cnt - 1;
  int gi1 = mTile * 128 + 64 + sr; if (gi1 >= cnt) gi1 = cnt - 1;
  const ushort* aP0 = hbuf + (size_t)(off + gi0) * DH + sc;
  const ushort* aP1 = hbuf + (size_t)(off + gi1) * DH + sc;
  const ushort* bP0 = w2t + ((size_t)e * DM + nTile * 128 + sr) * DH + sc;
  const ushort* bP1 = bP0 + (size_t)64 * DH;

  f32x4 zero = {0.f, 0.f, 0.f, 0.f};
  f32x4 acc[4][4];
#pragma unroll
  for (int i = 0; i < 4; i++)
#pragma unroll
    for (int j = 0; j < 4; j++) acc[i][j] = zero;

  const int quad = lane >> 4, lc = lane & 15;
  const int rq = quad ^ ((lc >> 1) & 3);

  auto compute = [&](const char* buf) {
    const char* A_ = buf;
    const char* B_ = buf + 8192;
    bf16x8 af[4], bfr[4];
#pragma unroll
    for (int mi = 0; mi < 4; mi++) {
      int row = wm * 64 + mi * 16 + lc;
      af[mi] = *(const bf16x8*)(A_ + row * 64 + rq * 16);
    }
#pragma unroll
    for (int ni = 0; ni < 4; ni++) {
      int row = wn * 64 + ni * 16 + lc;
      bfr[ni] = *(const bf16x8*)(B_ + row * 64 + rq * 16);
    }
#pragma unroll
    for (int mi = 0; mi < 4; mi++)
#pragma unroll
      for (int ni = 0; ni < 4; ni++)
        acc[mi][ni] = __builtin_amdgcn_mfma_f32_16x16x32_bf16(af[mi], bfr[ni], acc[mi][ni], 0, 0, 0);
  };

  const int NIT = DH / 32;  // 128
  STAGE_TILE(ldsB);
  STAGE_TILE(ldsB + 16384);
  int cur = 0;
  for (int tt = 0; tt < NIT - 1; ++tt) {
    asm volatile("s_waitcnt vmcnt(4)" ::: "memory");
    __builtin_amdgcn_s_barrier();
    if (tt + 2 < NIT) {
      int nx = cur + 2; if (nx >= 3) nx -= 3;
      STAGE_TILE(ldsB + nx * 16384);
    }
    compute(ldsB + cur * 16384);
    cur = (cur == 2) ? 0 : cur + 1;
  }
  asm volatile("s_waitcnt vmcnt(0)" ::: "memory");
  __builtin_amdgcn_s_barrier();
  compute(ldsB + cur * 16384);

  float bias[4];
#pragma unroll
  for (int ni = 0; ni < 4; ni++)
    bias[ni] = b2[(size_t)e * DM + nTile * 128 + wn * 64 + ni * 16 + lc];

#pragma unroll
  for (int mi = 0; mi < 4; mi++) {
#pragma unroll
    for (int r = 0; r < 4; r++) {
      int lr = wm * 64 + mi * 16 + quad * 4 + r;
      int gi = mTile * 128 + lr;
      if (gi < cnt) {
        int tok = tok_list[e * NT + gi];
        float s = scale_list[e * NT + gi];
        float* yrow = y + (size_t)tok * DM + nTile * 128 + wn * 64 + lc;
#pragma unroll
        for (int ni = 0; ni < 4; ni++) {
          float v = (acc[mi][ni][r] + bias[ni]) * s;
          unsafeAtomicAdd(&yrow[ni * 16], v);
        }
      }
    }
  }
}

extern "C" void kernel_launch(void* const* d_in, const int* in_sizes, int n_in,
                              void* d_out, int out_size, void* d_ws, size_t ws_size,
                              hipStream_t stream) {
  const float* inp = (const float*)d_in[0];
  const float* gw  = (const float*)d_in[1];
  const float* gb  = (const float*)d_in[2];
  const float* w1  = (const float*)d_in[3];
  const float* b1  = (const float*)d_in[4];
  const float* w2  = (const float*)d_in[5];
  const float* b2  = (const float*)d_in[6];
  float* y = (float*)d_out;

  // workspace layout (~286 MB total)
  char* ws = (char*)d_ws;
  ushort* inp_bf = (ushort*)ws;              ws += (size_t)NT * DM * 2;
  ushort* w1t    = (ushort*)ws;              ws += (size_t)NE * DH * DM * 2;
  ushort* w2t    = (ushort*)ws;              ws += (size_t)NE * DM * DH * 2;
  ushort* hbuf   = (ushort*)ws;              ws += (size_t)NP * DH * 2;
  int*    tok_list   = (int*)ws;             ws += (size_t)NE * NT * 4;
  float*  scale_list = (float*)ws;           ws += (size_t)NE * NT * 4;
  int*    counts     = (int*)ws;             ws += 256;

  hipMemsetAsync(counts, 0, 256, stream);

  // node 2: transpose (4096 blocks, 128x128 tiles) + gate (2048) + y-zero (2048)
  fused_pre_kernel<<<8192, 256, 0, stream>>>(w1, w2, w1t, w2t, inp, gw, gb,
                                             inp_bf, counts, tok_list, scale_list, y);
  // node 3: GEMM1 (r5-verified: 128^2, 3-buffer counted-vmcnt, swizzled)
  gemm1_kernel<<<NE * 32 * 64, 256, 0, stream>>>(inp_bf, w1t, b1, tok_list, counts, hbuf);
  // node 4: GEMM2 with fused scale+combine via atomics into y
  gemm2_kernel<<<NE * 8 * 64, 256, 0, stream>>>(hbuf, w2t, b2, tok_list, scale_list, counts, y);
}

// Round 10
// 766.529 us; speedup vs baseline: 1.4693x; 1.1806x over previous
//
#include <hip/hip_runtime.h>
#include <hip/hip_bf16.h>

#define NT 8192      // tokens
#define DM 1024      // d_model
#define NE 8         // experts
#define DH 4096      // d_hidden
#define NP (NT * 2)  // token-expert pairs (TOP_K = 2)

typedef __attribute__((ext_vector_type(8))) __bf16 bf16x8;
typedef __attribute__((ext_vector_type(4))) float f32x4;

__device__ __forceinline__ ushort f2bf(float f) {
  unsigned int x = __float_as_uint(f);
  unsigned int r = (x + 0x7fffu + ((x >> 16) & 1u)) >> 16;  // RNE
  return (ushort)r;
}

// exact tanh-gelu, rearranged: 0.5x(1+tanh(z)) = x*e^{2z}/(e^{2z}+1)
__device__ __forceinline__ float gelu_fast(float x) {
  float x2 = x * x;
  float t = __builtin_fmaf(x2, 0.044715f, 1.0f);
  float m = x * t * 2.3025851f;
  m = fminf(m, 126.0f);
  float p = __builtin_amdgcn_exp2f(m);
  return x * p * __builtin_amdgcn_rcpf(p + 1.0f);
}

__device__ __forceinline__ void async_copy16(const void* gsrc, void* ldst) {
  __builtin_amdgcn_global_load_lds(
      (const __attribute__((address_space(1))) void*)gsrc,
      (__attribute__((address_space(3))) void*)ldst, 16, 0, 0);
}

// ---------------- fused pre-pass: ONE kernel, four independent block ranges ----------------
//   b < 4096 : weight transpose+cvt (w1 -> w1t, w2 -> w2t), 128x128 tiles
//   b < 4224 : gating, BLOCK-AGGREGATED (128 blocks x 64 tokens)
//   b < 6272 : inp -> bf16 streaming cast (2048 blocks)
//   b < 8320 : zero y (gemm2 accumulates into y with atomics)
// r5/r6/r9 post-mortem: three different transpose implementations all pinned at
// ~284-288us -> the pin was the gate branch's 16384 same-line global atomicAdds
// (8 counters in one 32B line, ~1/30cyc at one L2 slice ~= 240-280us).
// Fix (Guideline 12): LDS-local per-expert append lists + 8 global atomics per
// block (1024 total, 16x fewer), then bulk copy-out.
__global__ __launch_bounds__(256) void fused_pre_kernel(
    const float* __restrict__ w1, const float* __restrict__ w2,
    ushort* __restrict__ w1t, ushort* __restrict__ w2t,
    const float* __restrict__ inp, const float* __restrict__ gw,
    const float* __restrict__ gb, ushort* __restrict__ inp_bf,
    int* __restrict__ counts, int* __restrict__ tok_list,
    float* __restrict__ scale_list, float* __restrict__ y) {
  __shared__ ushort tileT[128][136];   // transpose branch
  __shared__ int   lcnt[NE];           // gate branch
  __shared__ int   gbase[NE];
  __shared__ int   ltok[NE][64];       // per-token top2 experts are distinct -> <=64/expert
  __shared__ float lsc[NE][64];
  const int b = blockIdx.x;

  if (b < 4096) {
    // ---- transpose part: 128x128 tile, register 4x4 micro-transpose ----
    const int which = b >> 11;         // 0 = w1, 1 = w2
    const int rem = b & 2047;
    const int e = rem >> 8;            // expert
    const int bb = rem & 255;          // 256 tiles per expert-weight
    const float* src;
    ushort* dst;
    int R, C, r0, c0;
    if (which == 0) {
      src = w1 + (size_t)e * DM * DH; dst = w1t + (size_t)e * DM * DH;
      R = DM; C = DH;
      r0 = (bb & 7) * 128;   c0 = (bb >> 3) * 128;
    } else {
      src = w2 + (size_t)e * DM * DH; dst = w2t + (size_t)e * DM * DH;
      R = DH; C = DM;
      r0 = (bb & 31) * 128;  c0 = (bb >> 5) * 128;
    }
    const int tx = threadIdx.x & 31;
    const int ty = threadIdx.x >> 5;
#pragma unroll
    for (int i = 0; i < 4; i++) {
      int rb = ty + 8 * i;
      const float* sp = src + (size_t)(r0 + 4 * rb) * C + c0 + 4 * tx;
      float4 a0 = *(const float4*)(sp);
      float4 a1 = *(const float4*)(sp + C);
      float4 a2 = *(const float4*)(sp + 2 * (size_t)C);
      float4 a3 = *(const float4*)(sp + 3 * (size_t)C);
      ushort4 o0 = { f2bf(a0.x), f2bf(a1.x), f2bf(a2.x), f2bf(a3.x) };
      ushort4 o1 = { f2bf(a0.y), f2bf(a1.y), f2bf(a2.y), f2bf(a3.y) };
      ushort4 o2 = { f2bf(a0.z), f2bf(a1.z), f2bf(a2.z), f2bf(a3.z) };
      ushort4 o3 = { f2bf(a0.w), f2bf(a1.w), f2bf(a2.w), f2bf(a3.w) };
      *(ushort4*)(&tileT[4 * tx + 0][4 * rb]) = o0;
      *(ushort4*)(&tileT[4 * tx + 1][4 * rb]) = o1;
      *(ushort4*)(&tileT[4 * tx + 2][4 * rb]) = o2;
      *(ushort4*)(&tileT[4 * tx + 3][4 * rb]) = o3;
    }
    __syncthreads();
    const int kx = threadIdx.x & 31;
    const int ny = threadIdx.x >> 5;
#pragma unroll
    for (int i = 0; i < 16; i++) {
      int n = ny + 8 * i;
      *(ushort4*)(dst + (size_t)(c0 + n) * R + r0 + 4 * kx) =
          *(const ushort4*)(&tileT[n][4 * kx]);
    }
  } else if (b < 4224) {
    // ---- gating part: 64 tokens/block, block-aggregated appends ----
    const int t = threadIdx.x;
    if (t < NE) lcnt[t] = 0;
    __syncthreads();
    const int wave = t >> 6, lane = t & 63;
    const int tokBase = (b - 4096) * 64 + wave * 16;
    for (int ti = 0; ti < 16; ti++) {
      const int token = tokBase + ti;
      const float* x = inp + (size_t)token * DM;
      float acc[NE];
#pragma unroll
      for (int e = 0; e < NE; e++) acc[e] = 0.f;
#pragma unroll
      for (int j = 0; j < 16; j++) {
        int idx = j * 64 + lane;
        float xv = x[idx];
        const float4* g = (const float4*)(gw + (size_t)idx * NE);
        float4 g0 = g[0], g1 = g[1];
        acc[0] += xv * g0.x; acc[1] += xv * g0.y; acc[2] += xv * g0.z; acc[3] += xv * g0.w;
        acc[4] += xv * g1.x; acc[5] += xv * g1.y; acc[6] += xv * g1.z; acc[7] += xv * g1.w;
      }
#pragma unroll
      for (int e = 0; e < NE; e++) {
        for (int off = 32; off; off >>= 1) acc[e] += __shfl_xor(acc[e], off, 64);
      }
      if (lane == 0) {
        float v[NE];
#pragma unroll
        for (int e = 0; e < NE; e++) v[e] = acc[e] + gb[e];
        int i0 = 0; float b0 = v[0];
#pragma unroll
        for (int e = 1; e < NE; e++) if (v[e] > b0) { b0 = v[e]; i0 = e; }
        int i1 = -1; float b1v = -INFINITY;
#pragma unroll
        for (int e = 0; e < NE; e++) if (e != i0 && v[e] > b1v) { b1v = v[e]; i1 = e; }
        float s1 = 1.f / (1.f + __expf(b0 - b1v));  // softmax over the two selected logits
        float s0 = 1.f - s1;
        int p0 = atomicAdd(&lcnt[i0], 1);           // LDS atomic (fast)
        ltok[i0][p0] = token; lsc[i0][p0] = s0;
        int p1 = atomicAdd(&lcnt[i1], 1);
        ltok[i1][p1] = token; lsc[i1][p1] = s1;
      }
    }
    __syncthreads();
    if (t < NE) gbase[t] = atomicAdd(&counts[t], lcnt[t]);  // 8 global atomics/block
    __syncthreads();
#pragma unroll
    for (int e = 0; e < NE; e++) {
      int n = lcnt[e], gb0 = gbase[e];
      for (int s = t; s < n; s += 256) {
        tok_list[e * NT + gb0 + s] = ltok[e][s];
        scale_list[e * NT + gb0 + s] = lsc[e][s];
      }
    }
  } else if (b < 6272) {
    // ---- inp -> bf16 streaming cast: 2048 blocks x 4096 floats ----
    const int idx = b - 4224;
    const float4* s4 = (const float4*)(inp + (size_t)idx * 4096);
    ushort4* d4 = (ushort4*)(inp_bf + (size_t)idx * 4096);
    const int t = threadIdx.x;
#pragma unroll
    for (int j = 0; j < 4; j++) {
      float4 v = s4[t + j * 256];
      ushort4 o = { f2bf(v.x), f2bf(v.y), f2bf(v.z), f2bf(v.w) };
      d4[t + j * 256] = o;
    }
  } else {
    // ---- y-zero part: 2048 blocks x 4096 floats ----
    const int idx = b - 6272;
    float4* dst = (float4*)(y + (size_t)idx * 4096);
    f32x4 z = {0.f, 0.f, 0.f, 0.f};
#pragma unroll
    for (int j = 0; j < 4; j++)
      ((f32x4*)dst)[j * 256 + threadIdx.x] = z;
  }
}

// GEMM skeleton (round-5 verified champion): 128x128 tile, 256 thr (4 waves, 2x2),
// counted-vmcnt 3-buffer pipeline (T3/T4) + chunk-XOR LDS swizzle (T2, both-sides).
// Each wave issues exactly 4 loads per stage -> vmcnt(4) completes the oldest stage.

#define STAGE_TILE(base)                                      \
  do {                                                        \
    async_copy16(aP0, (char*)(base) + wv * 1024);             \
    async_copy16(aP1, (char*)(base) + 4096 + wv * 1024);      \
    async_copy16(bP0, (char*)(base) + 8192 + wv * 1024);      \
    async_copy16(bP1, (char*)(base) + 12288 + wv * 1024);     \
    aP0 += 32; aP1 += 32; bP0 += 32; bP1 += 32;               \
  } while (0)

// ---------------- GEMM1: h[off_e+gi] = gelu(x[tok] @ w1[e] + b1[e]), bf16 dense ----------------
__global__ __launch_bounds__(256) void gemm1_kernel(
    const ushort* __restrict__ xbf, const ushort* __restrict__ w1t,
    const float* __restrict__ b1, const int* __restrict__ tok_list,
    const int* __restrict__ counts, ushort* __restrict__ hbuf) {
  const int b = blockIdx.x;
  const int e = b & 7;
  const int idx = b >> 3;        // 0..2047
  const int mTile = idx & 63;    // fastest
  const int nTile = idx >> 6;    // 0..31
  int off = 0;
  for (int i = 0; i < e; i++) off += counts[i];
  const int cnt = counts[e];
  if (mTile * 128 >= cnt) return;

  __shared__ __attribute__((aligned(128))) char ldsB[49152];  // 3 x (A 8KB + B 8KB)

  const int t = threadIdx.x;
  const int lane = t & 63, wv = t >> 6;
  const int wm = wv & 1, wn = wv >> 1;

  const int sr = t >> 2;                             // staging row 0..63
  const int sc = (((t & 3) ^ ((sr >> 1) & 3)) * 8);  // swizzled source chunk (ushorts)
  int gi0 = mTile * 128 + sr;      if (gi0 >= cnt) gi0 = cnt - 1;
  int gi1 = mTile * 128 + 64 + sr; if (gi1 >= cnt) gi1 = cnt - 1;
  const int tok0 = tok_list[e * NT + gi0];
  const int tok1 = tok_list[e * NT + gi1];
  const ushort* aP0 = xbf + (size_t)tok0 * DM + sc;
  const ushort* aP1 = xbf + (size_t)tok1 * DM + sc;
  const ushort* bP0 = w1t + ((size_t)e * DH + nTile * 128 + sr) * DM + sc;
  const ushort* bP1 = bP0 + (size_t)64 * DM;

  f32x4 zero = {0.f, 0.f, 0.f, 0.f};
  f32x4 acc[4][4];
#pragma unroll
  for (int i = 0; i < 4; i++)
#pragma unroll
    for (int j = 0; j < 4; j++) acc[i][j] = zero;

  const int quad = lane >> 4, lc = lane & 15;
  const int rq = quad ^ ((lc >> 1) & 3);          // swizzled chunk for reads

  auto compute = [&](const char* buf) {
    const char* A_ = buf;
    const char* B_ = buf + 8192;
    bf16x8 af[4], bfr[4];
#pragma unroll
    for (int mi = 0; mi < 4; mi++) {
      int row = wm * 64 + mi * 16 + lc;
      af[mi] = *(const bf16x8*)(A_ + row * 64 + rq * 16);
    }
#pragma unroll
    for (int ni = 0; ni < 4; ni++) {
      int row = wn * 64 + ni * 16 + lc;
      bfr[ni] = *(const bf16x8*)(B_ + row * 64 + rq * 16);
    }
#pragma unroll
    for (int mi = 0; mi < 4; mi++)
#pragma unroll
      for (int ni = 0; ni < 4; ni++)
        acc[mi][ni] = __builtin_amdgcn_mfma_f32_16x16x32_bf16(af[mi], bfr[ni], acc[mi][ni], 0, 0, 0);
  };

  const int NIT = DM / 32;  // 32
  STAGE_TILE(ldsB);
  STAGE_TILE(ldsB + 16384);
  int cur = 0;
  for (int tt = 0; tt < NIT - 1; ++tt) {
    asm volatile("s_waitcnt vmcnt(4)" ::: "memory");
    __builtin_amdgcn_s_barrier();
    if (tt + 2 < NIT) {
      int nx = cur + 2; if (nx >= 3) nx -= 3;
      STAGE_TILE(ldsB + nx * 16384);
    }
    compute(ldsB + cur * 16384);
    cur = (cur == 2) ? 0 : cur + 1;
  }
  asm volatile("s_waitcnt vmcnt(0)" ::: "memory");
  __builtin_amdgcn_s_barrier();
  compute(ldsB + cur * 16384);

  float bias[4];
#pragma unroll
  for (int ni = 0; ni < 4; ni++)
    bias[ni] = b1[(size_t)e * DH + nTile * 128 + wn * 64 + ni * 16 + lc];

#pragma unroll
  for (int mi = 0; mi < 4; mi++) {
#pragma unroll
    for (int r = 0; r < 4; r++) {
      int lr = wm * 64 + mi * 16 + quad * 4 + r;
      int gi = mTile * 128 + lr;
      if (gi < cnt) {
        ushort* hrow = hbuf + (size_t)(off + gi) * DH + nTile * 128 + wn * 64 + lc;
#pragma unroll
        for (int ni = 0; ni < 4; ni++) {
          float v = acc[mi][ni][r] + bias[ni];
          hrow[ni * 16] = f2bf(gelu_fast(v));
        }
      }
    }
  }
}

// ---------------- GEMM2 (fused combine): y[tok] += s * (h @ w2[e] + b2[e]) ----------------
__global__ __launch_bounds__(256) void gemm2_kernel(
    const ushort* __restrict__ hbuf, const ushort* __restrict__ w2t,
    const float* __restrict__ b2, const int* __restrict__ tok_list,
    const float* __restrict__ scale_list, const int* __restrict__ counts,
    float* __restrict__ y) {
  const int b = blockIdx.x;
  const int e = b & 7;               // XCD pin
  const int idx = b >> 3;            // 0..511
  const int nTile = idx & 7;         // fastest: hbuf A-panel reuse
  const int mTile = idx >> 3;        // 0..63
  int off = 0;
  for (int i = 0; i < e; i++) off += counts[i];
  const int cnt = counts[e];
  if (mTile * 128 >= cnt) return;

  __shared__ __attribute__((aligned(128))) char ldsB[49152];  // 3 x (A 8KB + B 8KB)

  const int t = threadIdx.x;
  const int lane = t & 63, wv = t >> 6;
  const int wm = wv & 1, wn = wv >> 1;

  const int sr = t >> 2;
  const int sc = (((t & 3) ^ ((sr >> 1) & 3)) * 8);  // swizzled source chunk (ushorts)
  int gi0 = mTile * 128 + sr;      if (gi0 >= cnt) gi0 = cnt - 1;
  int gi1 = mTile * 128 + 64 + sr; if (gi1 >= cnt) gi1 = cnt - 1;
  const ushort* aP0 = hbuf + (size_t)(off + gi0) * DH + sc;
  const ushort* aP1 = hbuf + (size_t)(off + gi1) * DH + sc;
  const ushort* bP0 = w2t + ((size_t)e * DM + nTile * 128 + sr) * DH + sc;
  const ushort* bP1 = bP0 + (size_t)64 * DH;

  f32x4 zero = {0.f, 0.f, 0.f, 0.f};
  f32x4 acc[4][4];
#pragma unroll
  for (int i = 0; i < 4; i++)
#pragma unroll
    for (int j = 0; j < 4; j++) acc[i][j] = zero;

  const int quad = lane >> 4, lc = lane & 15;
  const int rq = quad ^ ((lc >> 1) & 3);

  auto compute = [&](const char* buf) {
    const char* A_ = buf;
    const char* B_ = buf + 8192;
    bf16x8 af[4], bfr[4];
#pragma unroll
    for (int mi = 0; mi < 4; mi++) {
      int row = wm * 64 + mi * 16 + lc;
      af[mi] = *(const bf16x8*)(A_ + row * 64 + rq * 16);
    }
#pragma unroll
    for (int ni = 0; ni < 4; ni++) {
      int row = wn * 64 + ni * 16 + lc;
      bfr[ni] = *(const bf16x8*)(B_ + row * 64 + rq * 16);
    }
#pragma unroll
    for (int mi = 0; mi < 4; mi++)
#pragma unroll
      for (int ni = 0; ni < 4; ni++)
        acc[mi][ni] = __builtin_amdgcn_mfma_f32_16x16x32_bf16(af[mi], bfr[ni], acc[mi][ni], 0, 0, 0);
  };

  const int NIT = DH / 32;  // 128
  STAGE_TILE(ldsB);
  STAGE_TILE(ldsB + 16384);
  int cur = 0;
  for (int tt = 0; tt < NIT - 1; ++tt) {
    asm volatile("s_waitcnt vmcnt(4)" ::: "memory");
    __builtin_amdgcn_s_barrier();
    if (tt + 2 < NIT) {
      int nx = cur + 2; if (nx >= 3) nx -= 3;
      STAGE_TILE(ldsB + nx * 16384);
    }
    compute(ldsB + cur * 16384);
    cur = (cur == 2) ? 0 : cur + 1;
  }
  asm volatile("s_waitcnt vmcnt(0)" ::: "memory");
  __builtin_amdgcn_s_barrier();
  compute(ldsB + cur * 16384);

  float bias[4];
#pragma unroll
  for (int ni = 0; ni < 4; ni++)
    bias[ni] = b2[(size_t)e * DM + nTile * 128 + wn * 64 + ni * 16 + lc];

#pragma unroll
  for (int mi = 0; mi < 4; mi++) {
#pragma unroll
    for (int r = 0; r < 4; r++) {
      int lr = wm * 64 + mi * 16 + quad * 4 + r;
      int gi = mTile * 128 + lr;
      if (gi < cnt) {
        int tok = tok_list[e * NT + gi];
        float s = scale_list[e * NT + gi];
        float* yrow = y + (size_t)tok * DM + nTile * 128 + wn * 64 + lc;
#pragma unroll
        for (int ni = 0; ni < 4; ni++) {
          float v = (acc[mi][ni][r] + bias[ni]) * s;
          unsafeAtomicAdd(&yrow[ni * 16], v);
        }
      }
    }
  }
}

extern "C" void kernel_launch(void* const* d_in, const int* in_sizes, int n_in,
                              void* d_out, int out_size, void* d_ws, size_t ws_size,
                              hipStream_t stream) {
  const float* inp = (const float*)d_in[0];
  const float* gw  = (const float*)d_in[1];
  const float* gb  = (const float*)d_in[2];
  const float* w1  = (const float*)d_in[3];
  const float* b1  = (const float*)d_in[4];
  const float* w2  = (const float*)d_in[5];
  const float* b2  = (const float*)d_in[6];
  float* y = (float*)d_out;

  // workspace layout (~286 MB total)
  char* ws = (char*)d_ws;
  ushort* inp_bf = (ushort*)ws;              ws += (size_t)NT * DM * 2;
  ushort* w1t    = (ushort*)ws;              ws += (size_t)NE * DH * DM * 2;
  ushort* w2t    = (ushort*)ws;              ws += (size_t)NE * DM * DH * 2;
  ushort* hbuf   = (ushort*)ws;              ws += (size_t)NP * DH * 2;
  int*    tok_list   = (int*)ws;             ws += (size_t)NE * NT * 4;
  float*  scale_list = (float*)ws;           ws += (size_t)NE * NT * 4;
  int*    counts     = (int*)ws;             ws += 256;

  hipMemsetAsync(counts, 0, 256, stream);

  // node 2: transpose (4096) + gate (128, block-aggregated) + cvt (2048) + y-zero (2048)
  fused_pre_kernel<<<8320, 256, 0, stream>>>(w1, w2, w1t, w2t, inp, gw, gb,
                                             inp_bf, counts, tok_list, scale_list, y);
  // node 3: GEMM1 (r5-verified: 128^2, 3-buffer counted-vmcnt, swizzled)
  gemm1_kernel<<<NE * 32 * 64, 256, 0, stream>>>(inp_bf, w1t, b1, tok_list, counts, hbuf);
  // node 4: GEMM2 with fused scale+combine via atomics into y
  gemm2_kernel<<<NE * 8 * 64, 256, 0, stream>>>(hbuf, w2t, b2, tok_list, scale_list, counts, y);
}